// Round 7
// baseline (158.134 us; speedup 1.0000x reference)
//
#include <hip/hip_runtime.h>
#include <math.h>

#define B_ 4096
#define T_ 64
#define V_ 512
#define E_ 32
#define H_ 128
#define FC1_ 256
#define O_ 1024

typedef float f32x4 __attribute__((ext_vector_type(4)));
typedef short s16x8 __attribute__((ext_vector_type(8)));
typedef unsigned short u16;

#define MFMA16(a, b, c) __builtin_amdgcn_mfma_f32_16x16x32_bf16(a, b, c, 0, 0, 0)

union Frag { u16 q[8]; unsigned u[4]; s16x8 v; };

__device__ __forceinline__ u16 f2bf(float f) {
    union { float f; unsigned u; } v; v.f = f;
    unsigned r = v.u + 0x7FFFu + ((v.u >> 16) & 1u);   // RNE
    return (u16)(r >> 16);
}
__device__ __forceinline__ unsigned cvtpk(float lo, float hi) {
    unsigned r;
    asm("v_cvt_pk_bf16_f32 %0, %1, %2" : "=v"(r) : "v"(lo), "v"(hi));
    return r;
}
__device__ __forceinline__ float sigf(float x) { return 1.0f / (1.0f + __expf(-x)); }
__device__ __forceinline__ float tanhfast(float x) {
    return 1.0f - 2.0f / (__expf(2.0f * x) + 1.0f);
}
// async global->LDS, 16B per lane: LDS dest = wave-uniform base + lane*16
__device__ __forceinline__ void gll16(const float* gsrc, float* ldst) {
    __builtin_amdgcn_global_load_lds(
        (const __attribute__((address_space(1))) unsigned int*)gsrc,
        (__attribute__((address_space(3))) unsigned int*)ldst,
        16, 0, 0);
}
// gather one B-fragment from fp32 weight row-major [rows][K]:
// frag[l][j] = W[(n0 + ln)*K + k0 + lh*8 + j]
__device__ __forceinline__ s16x8 gatherB(const float* W, int row, int K, int k0, int lh) {
    const float* p = W + (size_t)row * K + k0 + lh * 8;
    float4 a = *(const float4*)p;
    float4 b = *(const float4*)(p + 4);
    Frag f;
    f.u[0] = cvtpk(a.x, a.y); f.u[1] = cvtpk(a.z, a.w);
    f.u[2] = cvtpk(b.x, b.y); f.u[3] = cvtpk(b.z, b.w);
    return f.v;
}

// ---------------- single fused kernel: embed + GRU + FC1 + FC2 ---------------
// 256 blocks x 512 threads (8 waves); block owns 16 batch rows.
// Message streamed by global_load_lds: wave w loads rows {2w,2w+1} of one
// column as 4x contiguous 1KB instructions into mlds[2][16][516] (f32).
// x pipelined 2 steps ahead via epart/xfrag double buffers (as R6).
// One __syncthreads per step (drains vmcnt -> gll results visible to all).
__global__ void __launch_bounds__(512, 2) fused_kernel(
    const float* __restrict__ msg,
    const float* __restrict__ Wemb, const float* __restrict__ b_emb,
    const float* __restrict__ init_emb,
    const float* __restrict__ Wih, const float* __restrict__ Whh,
    const float* __restrict__ b_ih, const float* __restrict__ b_hh,
    const float* __restrict__ Wfc1, const float* __restrict__ b_fc1,
    const float* __restrict__ Wfc2, const float* __restrict__ b_fc2,
    float* __restrict__ out) {
    __shared__ float mlds[2][16][516];    // msg col staging (pad 4: even bank slots)
    __shared__ u16 hlds[2][16 * 136];     // h double buffer, row stride 136
    __shared__ float epart[2][8][576];    // embed partials dbuf, row stride 36
    __shared__ u16 xfrag[2][640];         // x bf16 A-frag staging, row stride 40
    __shared__ u16 hidl[16 * 264];        // FC1 out
    const int tid = threadIdx.x, w = tid >> 6, l = tid & 63;
    const int ln = l & 15, lh = l >> 4;
    const int wg = w & 3, wp = w >> 2;
    const int gb = blockIdx.x;

    for (int i = tid; i < 16 * 136; i += 512) hlds[0][i] = 0;

    // msg column streaming: wave w, instr i -> row 2w+(i>>1), half (i&1)
#define GLL_COL(C, BUF) do {                                                   \
    _Pragma("unroll")                                                          \
    for (int i_ = 0; i_ < 4; i_++) {                                           \
        int r_ = 2 * w + (i_ >> 1);                                            \
        int h_ = (i_ & 1) * 256;                                               \
        gll16(msg + ((size_t)(gb * 16 + r_) * T_ + (C)) * V_ + h_ + l * 4,     \
              &mlds[BUF][r_][h_]);                                             \
    }                                                                          \
} while (0)

    // ---- issue first two msg columns, then gather resident weights ----
    GLL_COL(0, 0);
    GLL_COL(1, 1);

    s16x8 wh[3][4], wi[3], we[2][2];
    float br, bz, bin, bgn;
    {
        #pragma unroll
        for (int g = 0; g < 3; g++) {
            int gt = wg + 4 * wp + 8 * g;
            #pragma unroll
            for (int kc = 0; kc < 4; kc++)
                wh[g][kc] = gatherB(Whh, gt * 16 + ln, 128, kc * 32, lh);
            wi[g] = gatherB(Wih, gt * 16 + ln, 32, 0, lh);
        }
        #pragma unroll
        for (int kk = 0; kk < 2; kk++) {
            we[kk][0] = gatherB(Wemb, ln, 512, (2 * w + kk) * 32, lh);
            we[kk][1] = gatherB(Wemb, 16 + ln, 512, (2 * w + kk) * 32, lh);
        }
        int c = wg * 16 + wp * 64 + ln;
        br  = b_ih[c] + b_hh[c];
        bz  = b_ih[128 + c] + b_hh[128 + c];
        bin = b_ih[256 + c];
        bgn = b_hh[256 + c];
    }
    const float bev = b_emb[tid & 31];
    s16x8 xinit;
    {
        Frag xi;
        #pragma unroll
        for (int j = 0; j < 8; j++) xi.q[j] = f2bf(init_emb[lh * 8 + j]);
        xinit = xi.v;
    }
    float hold[4] = {};
    __syncthreads();   // col0/col1 landed; hlds zeroed; weights gathered

    // embed partials of msg col in mlds[BUF] -> epart[PAR][w]  (x_{col+1})
#define EMBED_LDS(BUF, PAR) do {                                               \
    f32x4 e0 = {0.f, 0.f, 0.f, 0.f}, e1 = {0.f, 0.f, 0.f, 0.f};                \
    _Pragma("unroll")                                                          \
    for (int kk = 0; kk < 2; kk++) {                                           \
        const float* mp = &mlds[BUF][ln][(2 * w + kk) * 32 + lh * 8];          \
        f32x4 m0 = *(const f32x4*)mp;                                          \
        f32x4 m1 = *(const f32x4*)(mp + 4);                                    \
        Frag fa;                                                               \
        fa.u[0] = cvtpk(m0[0], m0[1]); fa.u[1] = cvtpk(m0[2], m0[3]);          \
        fa.u[2] = cvtpk(m1[0], m1[1]); fa.u[3] = cvtpk(m1[2], m1[3]);          \
        e0 = MFMA16(fa.v, we[kk][0], e0);                                      \
        e1 = MFMA16(fa.v, we[kk][1], e1);                                      \
    }                                                                          \
    _Pragma("unroll")                                                          \
    for (int i = 0; i < 4; i++) {                                              \
        epart[PAR][w][(lh * 4 + i) * 36 + ln]      = e0[i];                    \
        epart[PAR][w][(lh * 4 + i) * 36 + 16 + ln] = e1[i];                    \
    }                                                                          \
} while (0)

    // prologue embed: col 0 -> partials of x_1 -> epart[1]
    EMBED_LDS(0, 1);
    __syncthreads();

    const int aoff = ln * 136 + lh * 8;
    const int colo = wg * 16 + wp * 64 + ln;
    const int fr = tid >> 5, fc = tid & 31, fo = fr * 36 + fc;

#define GRU_STEP(TT) do {                                                      \
    const int t = (TT);                                                        \
    if (t <= 60) GLL_COL(t + 2, t & 1);                                        \
    const u16* hb = hlds[t & 1];                                               \
    s16x8 af0 = *(const s16x8*)(hb + aoff);                                    \
    s16x8 af1 = *(const s16x8*)(hb + aoff + 32);                               \
    s16x8 af2 = *(const s16x8*)(hb + aoff + 64);                               \
    s16x8 af3 = *(const s16x8*)(hb + aoff + 96);                               \
    s16x8 xc;                                                                  \
    if (t == 0) xc = xinit;                                                    \
    else xc = *(const s16x8*)(&xfrag[(t + 1) & 1][0] + ln * 40 + lh * 8);      \
    f32x4 ar  = {br, br, br, br};                                              \
    f32x4 az  = {bz, bz, bz, bz};                                              \
    f32x4 agn = {bgn, bgn, bgn, bgn};                                          \
    f32x4 ain = {bin, bin, bin, bin};                                          \
    ar  = MFMA16(xc, wi[0], ar);                                               \
    az  = MFMA16(xc, wi[1], az);                                               \
    ain = MFMA16(xc, wi[2], ain);                                              \
    ar  = MFMA16(af0, wh[0][0], ar);                                           \
    ar  = MFMA16(af1, wh[0][1], ar);                                           \
    ar  = MFMA16(af2, wh[0][2], ar);                                           \
    ar  = MFMA16(af3, wh[0][3], ar);                                           \
    az  = MFMA16(af0, wh[1][0], az);                                           \
    az  = MFMA16(af1, wh[1][1], az);                                           \
    az  = MFMA16(af2, wh[1][2], az);                                           \
    az  = MFMA16(af3, wh[1][3], az);                                           \
    agn = MFMA16(af0, wh[2][0], agn);                                          \
    agn = MFMA16(af1, wh[2][1], agn);                                          \
    agn = MFMA16(af2, wh[2][2], agn);                                          \
    agn = MFMA16(af3, wh[2][3], agn);                                          \
    u16* hw = hlds[(t + 1) & 1];                                               \
    float hn[4];                                                               \
    _Pragma("unroll")                                                          \
    for (int i = 0; i < 4; i++) {                                              \
        float rg = sigf(ar[i]);                                                \
        float zg = sigf(az[i]);                                                \
        float ng = tanhfast(ain[i] + rg * agn[i]);                             \
        hn[i] = zg * (hold[i] - ng) + ng;                                      \
        hold[i] = hn[i];                                                       \
    }                                                                          \
    {                                                                          \
        unsigned u01 = cvtpk(hn[0], hn[1]);                                    \
        unsigned u23 = cvtpk(hn[2], hn[3]);                                    \
        hw[(lh * 4 + 0) * 136 + colo] = (u16)(u01 & 0xFFFFu);                  \
        hw[(lh * 4 + 1) * 136 + colo] = (u16)(u01 >> 16);                      \
        hw[(lh * 4 + 2) * 136 + colo] = (u16)(u23 & 0xFFFFu);                  \
        hw[(lh * 4 + 3) * 136 + colo] = (u16)(u23 >> 16);                      \
    }                                                                          \
    if (t <= 61) EMBED_LDS((t + 1) & 1, t & 1);                                \
    if (t <= 62) {                                                             \
        const float* eb = &epart[(t + 1) & 1][0][0];                           \
        float s = eb[fo]           + eb[576 + fo]     + eb[2 * 576 + fo]       \
                + eb[3 * 576 + fo] + eb[4 * 576 + fo] + eb[5 * 576 + fo]       \
                + eb[6 * 576 + fo] + eb[7 * 576 + fo] + bev;                   \
        xfrag[t & 1][fr * 40 + fc] = f2bf(s);                                  \
    }                                                                          \
    __syncthreads();                                                           \
} while (0)

    for (int tt = 0; tt < 64; tt += 2) {
        GRU_STEP(tt);
        GRU_STEP(tt + 1);
    }
#undef GRU_STEP
#undef GLL_COL
#undef EMBED_LDS

    // ---- FC1: hid = elu(h @ W_fc1^T + b_fc1), [16][256]; wave w: ot = 2w,2w+1
    const u16* hb = hlds[0];   // final h in buffer (63+1)&1 = 0
    s16x8 hf0 = *(const s16x8*)(hb + aoff);
    s16x8 hf1 = *(const s16x8*)(hb + aoff + 32);
    s16x8 hf2 = *(const s16x8*)(hb + aoff + 64);
    s16x8 hf3 = *(const s16x8*)(hb + aoff + 96);
    #pragma unroll
    for (int q = 0; q < 2; q++) {
        int ot = 2 * w + q;
        float b1 = b_fc1[ot * 16 + ln];
        f32x4 a1 = {b1, b1, b1, b1};
        a1 = MFMA16(hf0, gatherB(Wfc1, ot * 16 + ln, 128, 0,  lh), a1);
        a1 = MFMA16(hf1, gatherB(Wfc1, ot * 16 + ln, 128, 32, lh), a1);
        a1 = MFMA16(hf2, gatherB(Wfc1, ot * 16 + ln, 128, 64, lh), a1);
        a1 = MFMA16(hf3, gatherB(Wfc1, ot * 16 + ln, 128, 96, lh), a1);
        #pragma unroll
        for (int i = 0; i < 4; i++) {
            float v = a1[i];
            v = v > 0.0f ? v : (__expf(v) - 1.0f);
            hidl[(lh * 4 + i) * 264 + ot * 16 + ln] = f2bf(v);
        }
    }
    __syncthreads();

    // ---- FC2: out = sigmoid(hid @ W_fc2^T + b_fc2); wave w: nt = 8w..8w+7
    s16x8 hf[8];
    #pragma unroll
    for (int kc = 0; kc < 8; kc++)
        hf[kc] = *(const s16x8*)(hidl + ln * 264 + kc * 32 + lh * 8);
    #pragma unroll
    for (int q = 0; q < 8; q++) {
        int nt = 8 * w + q;
        float b2 = b_fc2[nt * 16 + ln];
        f32x4 a2 = {b2, b2, b2, b2};
        #pragma unroll
        for (int kc = 0; kc < 8; kc++)
            a2 = MFMA16(hf[kc], gatherB(Wfc2, nt * 16 + ln, 256, kc * 32, lh), a2);
        #pragma unroll
        for (int i = 0; i < 4; i++)
            out[(size_t)(gb * 16 + lh * 4 + i) * 1024 + nt * 16 + ln] = sigf(a2[i]);
    }
}

extern "C" void kernel_launch(void* const* d_in, const int* in_sizes, int n_in,
                              void* d_out, int out_size, void* d_ws, size_t ws_size,
                              hipStream_t stream) {
    const float* message  = (const float*)d_in[0];
    const float* W_emb    = (const float*)d_in[1];
    const float* b_emb    = (const float*)d_in[2];
    const float* init_emb = (const float*)d_in[3];
    const float* W_ih     = (const float*)d_in[4];
    const float* W_hh     = (const float*)d_in[5];
    const float* b_ih     = (const float*)d_in[6];
    const float* b_hh     = (const float*)d_in[7];
    const float* W_fc1    = (const float*)d_in[8];
    const float* b_fc1    = (const float*)d_in[9];
    const float* W_fc2    = (const float*)d_in[10];
    const float* b_fc2    = (const float*)d_in[11];
    float* out = (float*)d_out;
    (void)d_ws; (void)ws_size;

    hipLaunchKernelGGL(fused_kernel, dim3(256), dim3(512), 0, stream,
                       message, W_emb, b_emb, init_emb, W_ih, W_hh, b_ih, b_hh,
                       W_fc1, b_fc1, W_fc2, b_fc2, out);
}